// Round 1
// baseline (71.133 us; speedup 1.0000x reference)
//
#include <hip/hip_runtime.h>

// AOLayer: out[b,n,a] = ang(b,n,a) * rad(b,n,a)
//   d   = pos[b,n,:] - centers[a,:]
//   r2  = |d|^2
//   rad = sum_p coeffs[a,p] * exp2(ke[a,p] * r2),  ke = -exps*log2(e)  (hoisted)
//   ang = prod_k f_k(d_k),  f(d) = a0 + d*(a1 + d*a2) with one-hot a0/a1/a2
// B=512, N=32, A=256, P=6. Output float32, 4M elems (16 MB).
//
// This version: 2 atoms per thread packed as float2 ext-vectors so the
// compiler can emit packed-FP32 (v_pk_fma_f32 / v_pk_mul_f32), halving
// VALU issue count; stores become global_store_dwordx2. Constants pack
// naturally (the two vector halves are DIFFERENT atoms, so no register
// duplication). pos loads remain block-uniform -> s_load.

#define BB 512
#define NN 32
#define AA 256
#define PP 6
#define BNPB 8       // bn's per block; grid = 16384/8 = 2048 blocks
#define THREADS 128  // thread t handles atoms 2t, 2t+1 (2 waves/block)

typedef float v2f __attribute__((ext_vector_type(2)));

#if defined(__has_builtin)
#  if __has_builtin(__builtin_amdgcn_exp2f)
#    define EXP2F(x) __builtin_amdgcn_exp2f(x)
#  else
#    define EXP2F(x) exp2f(x)
#  endif
#else
#  define EXP2F(x) exp2f(x)
#endif

__device__ __forceinline__ v2f splat2(float s) { v2f v; v.x = s; v.y = s; return v; }

__global__ __launch_bounds__(THREADS) void ao_kernel(
    const float* __restrict__ pos,      // (B*N, 3)
    const float* __restrict__ centers,  // (A, 3)
    const float* __restrict__ exps,     // (A, P)
    const float* __restrict__ coeffs,   // (A, P)
    const int*   __restrict__ powers,   // (A, 3)
    float*       __restrict__ out)      // (B*N, A)
{
    const int t   = threadIdx.x;        // 0..127
    const int a0  = t * 2;              // even atom
    const int a1  = a0 + 1;             // odd atom
    const int bn0 = blockIdx.x * BNPB;

    // Packed per-atom-pair constants (lane-private, live across bn loop).
    v2f cx; cx.x = centers[a0*3+0]; cx.y = centers[a1*3+0];
    v2f cy; cy.x = centers[a0*3+1]; cy.y = centers[a1*3+1];
    v2f cz; cz.x = centers[a0*3+2]; cz.y = centers[a1*3+2];

    v2f ke[PP], cf[PP];
#pragma unroll
    for (int p = 0; p < PP; ++p) {
        v2f e; e.x = exps[a0*PP+p]; e.y = exps[a1*PP+p];
        ke[p] = e * (-1.4426950408889634f);   // -log2(e)*exp
        cf[p].x = coeffs[a0*PP+p];
        cf[p].y = coeffs[a1*PP+p];
    }

    const int pwx0 = powers[a0*3+0], pwx1 = powers[a1*3+0];
    const int pwy0 = powers[a0*3+1], pwy1 = powers[a1*3+1];
    const int pwz0 = powers[a0*3+2], pwz1 = powers[a1*3+2];
    // one-hot polynomial coeffs: f(d) = A0 + d*(A1 + d*A2)
    v2f A0x, A1x, A2x, A0y, A1y, A2y, A0z, A1z, A2z;
    A0x.x = (pwx0 == 0) ? 1.0f : 0.0f;  A0x.y = (pwx1 == 0) ? 1.0f : 0.0f;
    A1x.x = (pwx0 == 1) ? 1.0f : 0.0f;  A1x.y = (pwx1 == 1) ? 1.0f : 0.0f;
    A2x.x = (pwx0 == 2) ? 1.0f : 0.0f;  A2x.y = (pwx1 == 2) ? 1.0f : 0.0f;
    A0y.x = (pwy0 == 0) ? 1.0f : 0.0f;  A0y.y = (pwy1 == 0) ? 1.0f : 0.0f;
    A1y.x = (pwy0 == 1) ? 1.0f : 0.0f;  A1y.y = (pwy1 == 1) ? 1.0f : 0.0f;
    A2y.x = (pwy0 == 2) ? 1.0f : 0.0f;  A2y.y = (pwy1 == 2) ? 1.0f : 0.0f;
    A0z.x = (pwz0 == 0) ? 1.0f : 0.0f;  A0z.y = (pwz1 == 0) ? 1.0f : 0.0f;
    A1z.x = (pwz0 == 1) ? 1.0f : 0.0f;  A1z.y = (pwz1 == 1) ? 1.0f : 0.0f;
    A2z.x = (pwz0 == 2) ? 1.0f : 0.0f;  A2z.y = (pwz1 == 2) ? 1.0f : 0.0f;

#pragma unroll
    for (int i = 0; i < BNPB; ++i) {
        const int bn = bn0 + i;
        // bn is block-uniform -> scalar (broadcast) loads.
        const float px = pos[bn * 3 + 0];
        const float py = pos[bn * 3 + 1];
        const float pz = pos[bn * 3 + 2];

        const v2f dx = splat2(px) - cx;
        const v2f dy = splat2(py) - cy;
        const v2f dz = splat2(pz) - cz;
        const v2f r2 = dx * dx + dy * dy + dz * dz;

        v2f rad; rad.x = 0.0f; rad.y = 0.0f;
#pragma unroll
        for (int p = 0; p < PP; ++p) {
            const v2f tt = ke[p] * r2;        // 1 pk-mul
            v2f e;
            e.x = EXP2F(tt.x);                // v_exp_f32 (scalar, trans pipe)
            e.y = EXP2F(tt.y);
            rad += cf[p] * e;                 // 1 pk-fma
        }

        const v2f fx = A0x + dx * (A1x + dx * A2x);   // 2 pk-fma each
        const v2f fy = A0y + dy * (A1y + dy * A2y);
        const v2f fz = A0z + dz * (A1z + dz * A2z);

        const v2f o = fx * fy * fz * rad;             // 3 pk-mul

        // atoms 2t,2t+1 are adjacent -> 8B-aligned dwordx2 store,
        // 512B contiguous per wave.
        *reinterpret_cast<v2f*>(&out[(size_t)bn * AA + a0]) = o;
    }
}

extern "C" void kernel_launch(void* const* d_in, const int* in_sizes, int n_in,
                              void* d_out, int out_size, void* d_ws, size_t ws_size,
                              hipStream_t stream) {
    const float* pos     = (const float*)d_in[0];  // (B,N,3)
    const float* centers = (const float*)d_in[1];  // (A,3)
    const float* exps    = (const float*)d_in[2];  // (A,P)
    const float* coeffs  = (const float*)d_in[3];  // (A,P)
    const int*   powers  = (const int*)d_in[4];    // (A,3)
    float* out = (float*)d_out;                    // (B,N,A)

    const int total_bn = BB * NN;                  // 16384
    const int grid = total_bn / BNPB;              // 2048 blocks
    ao_kernel<<<grid, THREADS, 0, stream>>>(pos, centers, exps, coeffs, powers, out);
}